// Round 20
// baseline (1618.069 us; speedup 1.0000x reference)
//
#include <hip/hip_runtime.h>

#define T_ 96
#define N_ 1140
#define F_ 64
#define H_ 32
#define E_ 22800
#define LH_ 250
#define G4_ 1000
#define OUT_ 2280
#define KIN_ 36480   // N_*H_
#define KINH 18240   // KIN_/2 (f16 pairs)
#define SPLITK 60
#define KC 32
#define BN 32
#define FEATB 13680  // feat blocks (109440 rows / 8)

typedef _Float16 h2_t __attribute__((ext_vector_type(2)));

__device__ __forceinline__ float leaky02(float x){ return x > 0.f ? x : 0.2f*x; }
__device__ __forceinline__ float fsigm(float x){ return 1.f/(1.f + __expf(-x)); }
__device__ __forceinline__ float ftanh(float x){
  x = fminf(fmaxf(x, -15.f), 15.f);
  float t = __expf(2.f * x);
  return (t - 1.f) / (t + 1.f);
}
__device__ __forceinline__ unsigned packh2(float a, float b) {
  auto p = __builtin_amdgcn_cvt_pkrtz(a, b);   // __fp16 ext_vector(2)
  return __builtin_bit_cast(unsigned, p);
}
__device__ __forceinline__ float fdot2u(unsigned w, unsigned h, float acc) {
  return __builtin_amdgcn_fdot2(__builtin_bit_cast(h2_t, w),
                                __builtin_bit_cast(h2_t, h), acc, false);
}

// relaxed agent-scope atomics -> sc1 ops at the coherence point, no L2 wb/inv
__device__ __forceinline__ void st_agent_u(unsigned* p, unsigned v) {
  __hip_atomic_store(p, v, __ATOMIC_RELAXED, __HIP_MEMORY_SCOPE_AGENT);
}
__device__ __forceinline__ unsigned ld_agent_u(const unsigned* p) {
  return __hip_atomic_load((unsigned*)p, __ATOMIC_RELAXED, __HIP_MEMORY_SCOPE_AGENT);
}
__device__ __forceinline__ void st_agent_i(int* p, int v) {
  __hip_atomic_store(p, v, __ATOMIC_RELAXED, __HIP_MEMORY_SCOPE_AGENT);
}
__device__ __forceinline__ int ld_agent_i(const int* p) {
  return __hip_atomic_load((int*)p, __ATOMIC_RELAXED, __HIP_MEMORY_SCOPE_AGENT);
}

// -- fused grid: GAT-1 feature (blocks 0..FEATB-1) || per-graph CSR build --
__global__ void k_featcsr(const float* __restrict__ x, const float* __restrict__ W,
                          const float* __restrict__ as_, const float* __restrict__ ad_,
                          float* __restrict__ Hout, float* __restrict__ HS,
                          float* __restrict__ HD,
                          const int* __restrict__ ei, int* __restrict__ offs,
                          int* __restrict__ elist) {
  __shared__ float Wl[F_ * H_];
  __shared__ float asl[32], adl[32];
  __shared__ int cnt[N_], cur[N_], sh[256];
  int tid = threadIdx.x;
  if (blockIdx.x >= FEATB) {
    // ---------- CSR build for graph t ----------
    int t = blockIdx.x - FEATB;
    const int* srcp = ei + (size_t)t * 2 * E_;
    const int* dstp = srcp + E_;
    for (int i = tid; i < N_; i += 256) cnt[i] = 0;
    __syncthreads();
    for (int k = tid; k < E_; k += 256) atomicAdd(&cnt[dstp[k]], 1);
    __syncthreads();
    // scan (1140 = 256 threads x 5)
    int base = tid * 5;
    int v[5]; int s = 0;
    #pragma unroll
    for (int r = 0; r < 5; ++r) {
      int i = base + r;
      int c = (i < N_) ? cnt[i] : 0;
      v[r] = c; s += c;
    }
    sh[tid] = s; __syncthreads();
    for (int off = 1; off < 256; off <<= 1) {
      int add = (tid >= off) ? sh[tid - off] : 0;
      __syncthreads();
      sh[tid] += add;
      __syncthreads();
    }
    int run = sh[tid] - s;
    #pragma unroll
    for (int r = 0; r < 5; ++r) {
      int i = base + r;
      if (i < N_) { offs[t * (N_ + 1) + i] = run; cur[i] = run; }
      run += v[r];
    }
    if (tid == 255) offs[t * (N_ + 1) + N_] = sh[255];
    __syncthreads();
    // fill with LDS cursors
    int* elt = elist + (size_t)t * E_;
    for (int k = tid; k < E_; k += 256) {
      int src = srcp[k];
      int pos = atomicAdd(&cur[dstp[k]], 1);
      elt[pos] = src;
    }
    return;
  }
  // ---------- GAT-1 feature transform ----------
  for (int i = tid; i < F_ * H_; i += 256) Wl[i] = W[i];
  if (tid < 32) { asl[tid] = as_[tid]; adl[tid] = ad_[tid]; }
  __syncthreads();
  int row = blockIdx.x * 8 + (tid >> 5);
  int c = tid & 31;
  const float4* xr = (const float4*)(x + (size_t)row * F_);
  float acc = 0.f;
  for (int k4 = 0; k4 < (F_ >> 2); ++k4) {
    float4 v = xr[k4];
    acc += v.x * Wl[(4 * k4 + 0) * H_ + c];
    acc += v.y * Wl[(4 * k4 + 1) * H_ + c];
    acc += v.z * Wl[(4 * k4 + 2) * H_ + c];
    acc += v.w * Wl[(4 * k4 + 3) * H_ + c];
  }
  Hout[(size_t)row * H_ + c] = acc;
  float ps = acc * asl[c], pd = acc * adl[c];
  #pragma unroll
  for (int off = 16; off > 0; off >>= 1) {
    ps += __shfl_xor(ps, off, 32);
    pd += __shfl_xor(pd, off, 32);
  }
  if (c == 0) { HS[row] = ps; HD[row] = pd; }
}

// ------ fused: GAT-1 aggregate + GAT-2 feature, LDS-resident per graph -----
// One block per graph: stage H (146KB) + HS/HD (9KB) + W2 (4KB) in LDS;
// all gathers hit LDS instead of L2. 159,392 B LDS total.
__global__ void __launch_bounds__(256) k_aggrfeat(
    const float* __restrict__ Hf, const float* __restrict__ HS,
    const float* __restrict__ HD, const int* __restrict__ offs,
    const int* __restrict__ elist, const float* __restrict__ b,
    const float* __restrict__ W2, const float* __restrict__ as2,
    const float* __restrict__ ad2,
    float* __restrict__ H2, float* __restrict__ HS2, float* __restrict__ HD2) {
  __shared__ float ldsH[N_ * H_];
  __shared__ float ldsHS[N_], ldsHD[N_];
  __shared__ float W2l[H_ * H_];
  __shared__ float as2l[32], ad2l[32];
  int t = blockIdx.x;
  int tid = threadIdx.x;
  {
    const float4* s4 = (const float4*)(Hf + (size_t)t * N_ * H_);
    float4* d4 = (float4*)ldsH;
    for (int i = tid; i < N_ * H_ / 4; i += 256) d4[i] = s4[i];
    for (int i = tid; i < N_; i += 256) {
      ldsHS[i] = HS[t * N_ + i];
      ldsHD[i] = HD[t * N_ + i];
    }
    for (int i = tid; i < H_ * H_; i += 256) W2l[i] = W2[i];
    if (tid < 32) { as2l[tid] = as2[tid]; ad2l[tid] = ad2[tid]; }
  }
  __syncthreads();
  const int* el = elist + (size_t)t * E_;
  const int* offt = offs + t * (N_ + 1);
  int c = tid & 31;
  for (int ib = 0; ib < N_; ib += 8) {
    int i = ib + (tid >> 5);
    if (i >= N_) continue;
    int row = t * N_ + i;
    float hd_i = ldsHD[i];
    float m = leaky02(ldsHS[i] + hd_i);   // self-loop
    float s = 1.f;
    float acc = ldsH[i * H_ + c];
    int e0 = offt[i], e1 = offt[i + 1];
    for (int base = e0; base < e1; base += 32) {
      int e = base + c;
      bool valid = (e < e1);
      int src = valid ? el[e] : 0;
      float eg = valid ? leaky02(ldsHS[src] + hd_i) : -1e30f;
      float M = eg;
      #pragma unroll
      for (int off = 16; off > 0; off >>= 1) M = fmaxf(M, __shfl_xor(M, off, 32));
      float mn = fmaxf(m, M);
      float scl = __expf(m - mn);
      float p = __expf(eg - mn);
      float ps = p;
      #pragma unroll
      for (int off = 16; off > 0; off >>= 1) ps += __shfl_xor(ps, off, 32);
      s = s * scl + ps;
      acc *= scl;
      int cnt2 = e1 - base; if (cnt2 > 32) cnt2 = 32;
      for (int l = 0; l < cnt2; ++l) {
        float pb = __shfl(p, l, 32);
        int sb = __shfl(src, l, 32);
        acc += pb * ldsH[sb * H_ + c];   // LDS gather
      }
      m = mn;
    }
    float val = fmaxf(acc / s + b[c], 0.f);   // relu'd X1, in-register
    // ---- GAT-2 feature via shfl broadcasts ----
    float acc2 = 0.f;
    #pragma unroll
    for (int cc = 0; cc < 32; ++cc) {
      float xc = __shfl(val, cc, 32);
      acc2 += xc * W2l[cc * H_ + c];
    }
    H2[(size_t)row * H_ + c] = acc2;
    float ps2 = acc2 * as2l[c], pd2 = acc2 * ad2l[c];
    #pragma unroll
    for (int off = 16; off > 0; off >>= 1) {
      ps2 += __shfl_xor(ps2, off, 32);
      pd2 += __shfl_xor(pd2, off, 32);
    }
    if (c == 0) { HS2[row] = ps2; HD2[row] = pd2; }
  }
}

// --------- GAT-2 aggregate, LDS-resident; emits f16-packed X2h -------------
__global__ void __launch_bounds__(256) k_aggr(
    const float* __restrict__ Hf, const float* __restrict__ HS,
    const float* __restrict__ HD, const int* __restrict__ offs,
    const int* __restrict__ elist, const float* __restrict__ b,
    unsigned* __restrict__ X2h) {
  __shared__ float ldsH[N_ * H_];
  __shared__ float ldsHS[N_], ldsHD[N_];
  __shared__ float bl[32];
  int t = blockIdx.x;
  int tid = threadIdx.x;
  {
    const float4* s4 = (const float4*)(Hf + (size_t)t * N_ * H_);
    float4* d4 = (float4*)ldsH;
    for (int i = tid; i < N_ * H_ / 4; i += 256) d4[i] = s4[i];
    for (int i = tid; i < N_; i += 256) {
      ldsHS[i] = HS[t * N_ + i];
      ldsHD[i] = HD[t * N_ + i];
    }
    if (tid < 32) bl[tid] = b[tid];
  }
  __syncthreads();
  const int* el = elist + (size_t)t * E_;
  const int* offt = offs + t * (N_ + 1);
  int c = tid & 31;
  for (int ib = 0; ib < N_; ib += 8) {
    int i = ib + (tid >> 5);
    if (i >= N_) continue;
    float hd_i = ldsHD[i];
    float m = leaky02(ldsHS[i] + hd_i);   // self-loop
    float s = 1.f;
    float acc = ldsH[i * H_ + c];
    int e0 = offt[i], e1 = offt[i + 1];
    for (int base = e0; base < e1; base += 32) {
      int e = base + c;
      bool valid = (e < e1);
      int src = valid ? el[e] : 0;
      float eg = valid ? leaky02(ldsHS[src] + hd_i) : -1e30f;
      float M = eg;
      #pragma unroll
      for (int off = 16; off > 0; off >>= 1) M = fmaxf(M, __shfl_xor(M, off, 32));
      float mn = fmaxf(m, M);
      float scl = __expf(m - mn);
      float p = __expf(eg - mn);
      float ps = p;
      #pragma unroll
      for (int off = 16; off > 0; off >>= 1) ps += __shfl_xor(ps, off, 32);
      s = s * scl + ps;
      acc *= scl;
      int cnt2 = e1 - base; if (cnt2 > 32) cnt2 = 32;
      for (int l = 0; l < cnt2; ++l) {
        float pb = __shfl(p, l, 32);
        int sb = __shfl(src, l, 32);
        acc += pb * ldsH[sb * H_ + c];
      }
      m = mn;
    }
    float val = acc / s + bl[c];
    // pack f16 pairs (same quantization k_gemm applied before -> G0 identical)
    int cp = c & ~1;
    float v0 = __shfl(val, cp, 32);
    float v1 = __shfl(val, cp + 1, 32);
    if ((c & 1) == 0)
      X2h[(size_t)t * KINH + i * 16 + (c >> 1)] = packh2(v0, v1);
  }
}

// ------- LSTM0 input GEMM (f16 dot2), X pre-packed: halves X traffic -------
__global__ void k_gemm(const unsigned* __restrict__ Xh, const float* __restrict__ Wih,
                       float* __restrict__ Gpart) {
  __shared__ unsigned Xs[T_][KC / 2 + 1];   // f16 pairs along K
  __shared__ unsigned Ws[BN][KC / 2 + 1];
  int j0 = blockIdx.x * BN;
  int sp = blockIdx.y;
  int tid = threadIdx.x;
  int jj = tid & 7;    // 8 j-groups of 4
  int tt = tid >> 3;   // 16 t-groups of 6
  float acc[6][4] = {};
  int kbeg = sp * (KIN_ / SPLITK);
  int kend = kbeg + (KIN_ / SPLITK);
  for (int k0 = kbeg; k0 < kend; k0 += KC) {
    for (int idx = tid; idx < T_ * (KC / 2); idx += 128) {
      int tr = idx >> 4; int kk = idx & 15;
      Xs[tr][kk] = Xh[(size_t)tr * KINH + (k0 >> 1) + kk];
    }
    for (int idx = tid; idx < BN * (KC / 2); idx += 128) {
      int jr = idx >> 4; int kk = idx & 15;
      int j = j0 + jr;
      unsigned v = 0;
      if (j < G4_) {
        const float2 w = *(const float2*)(Wih + (size_t)j * KIN_ + k0 + 2 * kk);
        v = packh2(w.x, w.y);
      }
      Ws[jr][kk] = v;
    }
    __syncthreads();
    for (int kk = 0; kk < KC / 2; ++kk) {
      unsigned xv[6], wv[4];
      #pragma unroll
      for (int r = 0; r < 6; ++r) xv[r] = Xs[tt * 6 + r][kk];
      #pragma unroll
      for (int q = 0; q < 4; ++q) wv[q] = Ws[jj * 4 + q][kk];
      #pragma unroll
      for (int r = 0; r < 6; ++r)
        #pragma unroll
        for (int q = 0; q < 4; ++q)
          acc[r][q] = fdot2u(wv[q], xv[r], acc[r][q]);
    }
    __syncthreads();
  }
  #pragma unroll
  for (int r = 0; r < 6; ++r) {
    int t = tt * 6 + r;
    #pragma unroll
    for (int q = 0; q < 4; ++q) {
      int j = j0 + jj * 4 + q;
      if (j < G4_) Gpart[((size_t)sp * T_ + t) * 1024 + j] = acc[r][q];
    }
  }
}

// G0 reduced with gate-interleaved layout: G0[t*1000 + j*4 + g]
__global__ void k_gred(const float* __restrict__ Gpart, const float* __restrict__ bih,
                       const float* __restrict__ bhh, float* __restrict__ G0) {
  int idx = blockIdx.x * blockDim.x + threadIdx.x;
  if (idx >= T_ * G4_) return;
  int t = idx / G4_; int jg = idx - t * G4_;
  int j = jg >> 2, g = jg & 3;
  int c = g * LH_ + j;                      // gate-major column in Gpart
  float s = bih[c] + bhh[c];
  for (int sp = 0; sp < SPLITK; ++sp) s += Gpart[((size_t)sp * T_ + t) * 1024 + c];
  G0[idx] = s;
}

// ---------------- 8-WG register-resident 2-layer LSTM (R8-proven) ----------
__global__ void __launch_bounds__(512, 2) k_lstm(
    const float* __restrict__ G0, const float* __restrict__ Whh0,
    const float* __restrict__ Wih1, const float* __restrict__ Whh1,
    const float* __restrict__ bih1, const float* __restrict__ bhh1,
    const float* __restrict__ h0in, const float* __restrict__ c0in,
    unsigned* __restrict__ hp,     // [2 slots][2 layers][128] f16-pairs
    int* __restrict__ flags,       // [8], zeroed by memset
    float* __restrict__ ylast) {
  int tid = threadIdx.x;
  int bid = blockIdx.x;
  int wv = bid * 8 + (tid >> 6);   // 0..63
  int lane = tid & 63;
  int qg = lane >> 4;              // gate: 0=i 1=f 2=g 3=o
  int ql = lane & 15;

  unsigned w0[4][8], wx1[4][8], wh1[4][8];
  float bs1[4], c0l[4], c1l[4];
  bool act[4];
  #pragma unroll
  for (int u = 0; u < 4; ++u) {
    int U = wv * 4 + u;
    act[u] = (U < LH_);
    int Uc = act[u] ? U : 0;
    size_t rb = (size_t)(qg * LH_ + Uc) * LH_;
    #pragma unroll
    for (int m = 0; m < 8; ++m) {
      int pi = m * 16 + ql;
      if (act[u] && pi < 125) {
        w0[u][m]  = packh2(Whh0[rb + 2 * pi], Whh0[rb + 2 * pi + 1]);
        wx1[u][m] = packh2(Wih1[rb + 2 * pi], Wih1[rb + 2 * pi + 1]);
        wh1[u][m] = packh2(Whh1[rb + 2 * pi], Whh1[rb + 2 * pi + 1]);
      } else { w0[u][m] = 0; wx1[u][m] = 0; wh1[u][m] = 0; }
    }
    bs1[u] = act[u] ? (bih1[qg * LH_ + Uc] + bhh1[qg * LH_ + Uc]) : 0.f;
    c0l[u] = act[u] ? c0in[Uc] : 0.f;
    c1l[u] = act[u] ? c0in[LH_ + Uc] : 0.f;
  }

  float gpre[4];
  #pragma unroll
  for (int u = 0; u < 4; ++u)
    gpre[u] = act[u] ? G0[0 * G4_ + (wv * 4 + u) * 4 + qg] : 0.f;

  for (int p = 0; p <= T_; ++p) {
    int rs = (p - 1) & 1, wslot = p & 1;
    unsigned x0p[8], h1p[8];
    // x0p = h0[p-1] (= layer0 recurrent input AND layer1 x input)
    if (p == 0) {
      #pragma unroll
      for (int m = 0; m < 8; ++m) {
        int pi = m * 16 + ql;
        x0p[m] = (pi < 125) ? packh2(h0in[2 * pi], h0in[2 * pi + 1]) : 0u;
      }
    } else {
      #pragma unroll
      for (int m = 0; m < 8; ++m)
        x0p[m] = ld_agent_u(&hp[rs * 256 + m * 16 + ql]);
      if (p == 1) {
        #pragma unroll
        for (int m = 0; m < 8; ++m) {
          int pi = m * 16 + ql;
          h1p[m] = (pi < 125) ? packh2(h0in[LH_ + 2 * pi], h0in[LH_ + 2 * pi + 1]) : 0u;
        }
      } else {
        #pragma unroll
        for (int m = 0; m < 8; ++m)
          h1p[m] = ld_agent_u(&hp[rs * 256 + 128 + m * 16 + ql]);
      }
    }

    // ---- layer 0, step p ----
    if (p < T_) {
      float h0new[4];
      #pragma unroll
      for (int u = 0; u < 4; ++u) {
        float s = 0.f;
        #pragma unroll
        for (int m = 0; m < 8; ++m) s = fdot2u(w0[u][m], x0p[m], s);
        s += __shfl_xor(s, 1); s += __shfl_xor(s, 2);
        s += __shfl_xor(s, 4); s += __shfl_xor(s, 8);
        float pre = s + gpre[u];
        float a = (qg == 2) ? ftanh(pre) : fsigm(pre);
        float ai = __shfl(a, ql);
        float af = __shfl(a, 16 + ql);
        float ag = __shfl(a, 32 + ql);
        float ao = __shfl(a, 48 + ql);
        c0l[u] = af * c0l[u] + ai * ag;
        h0new[u] = act[u] ? (ao * ftanh(c0l[u])) : 0.f;
      }
      if (lane == 0) {
        st_agent_u(&hp[wslot * 256 + 2 * wv],     packh2(h0new[0], h0new[1]));
        st_agent_u(&hp[wslot * 256 + 2 * wv + 1], packh2(h0new[2], h0new[3]));
      }
    }
    // ---- layer 1, step p-1 ----
    if (p >= 1) {
      float h1new[4];
      #pragma unroll
      for (int u = 0; u < 4; ++u) {
        float s = 0.f;
        #pragma unroll
        for (int m = 0; m < 8; ++m) s = fdot2u(wx1[u][m], x0p[m], s);
        #pragma unroll
        for (int m = 0; m < 8; ++m) s = fdot2u(wh1[u][m], h1p[m], s);
        s += __shfl_xor(s, 1); s += __shfl_xor(s, 2);
        s += __shfl_xor(s, 4); s += __shfl_xor(s, 8);
        float pre = s + bs1[u];
        float a = (qg == 2) ? ftanh(pre) : fsigm(pre);
        float bi = __shfl(a, ql);
        float bf = __shfl(a, 16 + ql);
        float bg = __shfl(a, 32 + ql);
        float bo = __shfl(a, 48 + ql);
        c1l[u] = bf * c1l[u] + bi * bg;
        h1new[u] = act[u] ? (bo * ftanh(c1l[u])) : 0.f;
      }
      if (p - 1 == T_ - 1 && lane == 0) {
        #pragma unroll
        for (int u = 0; u < 4; ++u)
          if (act[u]) ylast[wv * 4 + u] = h1new[u];
      }
      if (lane == 0) {
        st_agent_u(&hp[wslot * 256 + 128 + 2 * wv],     packh2(h1new[0], h1new[1]));
        st_agent_u(&hp[wslot * 256 + 128 + 2 * wv + 1], packh2(h1new[2], h1new[3]));
      }
    }
    // ---- prefetch next step's G0 (independent of the barrier) ----
    float gnext[4];
    #pragma unroll
    for (int u = 0; u < 4; ++u)
      gnext[u] = (p + 1 < T_ && act[u]) ? G0[(p + 1) * G4_ + (wv * 4 + u) * 4 + qg] : 0.f;
    // ---- fence-free barrier ----
    if (p < T_) {
      __syncthreads();   // implicit vmcnt drain: all sc1 stores acked
      if (tid == 0) {
        asm volatile("s_waitcnt vmcnt(0)" ::: "memory");
        st_agent_i(&flags[bid], p + 1);
      }
      if (tid < 64) {
        int guard = 0;
        for (;;) {
          int f = ld_agent_i(&flags[lane & 7]);
          if (__ballot(f >= p + 1) == ~0ULL) break;
          if (++guard > (1 << 22)) break;   // hang insurance only
          __builtin_amdgcn_s_sleep(1);
        }
      }
      __syncthreads();
    }
    #pragma unroll
    for (int u = 0; u < 4; ++u) gpre[u] = gnext[u];
  }
}

// ---------------- 4 FC heads ----------------------------------------------
__global__ void k_fc(const float* __restrict__ ylast,
                     const float* __restrict__ Wa, const float* __restrict__ ba,
                     const float* __restrict__ Wb, const float* __restrict__ bb,
                     const float* __restrict__ Wc, const float* __restrict__ bc,
                     const float* __restrict__ Wd, const float* __restrict__ bd,
                     float* __restrict__ out) {
  int wg = blockIdx.x * 4 + (threadIdx.x >> 6);
  int lane = threadIdx.x & 63;
  if (wg >= 4 * OUT_) return;
  int head = wg / OUT_, o = wg - head * OUT_;
  const float* W = head == 0 ? Wa : head == 1 ? Wb : head == 2 ? Wc : Wd;
  const float* b = head == 0 ? ba : head == 1 ? bb : head == 2 ? bc : bd;
  float s = 0.f;
  #pragma unroll
  for (int r = 0; r < 4; ++r) {
    int idx = r * 64 + lane;
    if (idx < LH_) s += ylast[idx] * W[(size_t)o * LH_ + idx];
  }
  #pragma unroll
  for (int off = 32; off > 0; off >>= 1) s += __shfl_xor(s, off, 64);
  if (lane == 0) out[wg] = s + b[o];
}

// ---------------- launch ---------------------------------------------------
extern "C" void kernel_launch(void* const* d_in, const int* in_sizes, int n_in,
                              void* d_out, int out_size, void* d_ws, size_t ws_size,
                              hipStream_t stream) {
  const float* nodes = (const float*)d_in[0];
  const int*   ei    = (const int*)d_in[1];
  const float* W1    = (const float*)d_in[3];
  const float* as1   = (const float*)d_in[4];
  const float* ad1   = (const float*)d_in[5];
  const float* b1    = (const float*)d_in[6];
  const float* W2    = (const float*)d_in[7];
  const float* as2   = (const float*)d_in[8];
  const float* ad2   = (const float*)d_in[9];
  const float* b2    = (const float*)d_in[10];
  const float* Wih0  = (const float*)d_in[11];
  const float* Whh0  = (const float*)d_in[12];
  const float* bih0  = (const float*)d_in[13];
  const float* bhh0  = (const float*)d_in[14];
  const float* Wih1  = (const float*)d_in[15];
  const float* Whh1  = (const float*)d_in[16];
  const float* bih1  = (const float*)d_in[17];
  const float* bhh1  = (const float*)d_in[18];
  const float* h0    = (const float*)d_in[19];
  const float* c0    = (const float*)d_in[20];
  const float* fW1   = (const float*)d_in[21];
  const float* fb1   = (const float*)d_in[22];
  const float* fW2   = (const float*)d_in[23];
  const float* fb2   = (const float*)d_in[24];
  const float* fW3   = (const float*)d_in[25];
  const float* fb3   = (const float*)d_in[26];
  const float* fW4   = (const float*)d_in[27];
  const float* fb4   = (const float*)d_in[28];
  float* out = (float*)d_out;

  // workspace layout (bytes). Gpart overlaps the dead H1/HS/HD/H2 prefix.
  const size_t o_Gpart  = 0;          // 23,592,960
  const size_t o_H      = 0;          // H1 14,008,320
  const size_t o_HS     = 14008320;   // 437,760
  const size_t o_HD     = 14446080;   // 437,760
  const size_t o_H2     = 14883840;   // 14,008,320
  const size_t o_X2h    = 28892160;   // 96*18240*4 = 7,004,160 (f16 pairs)
  const size_t o_flags  = 35896320;   // 256
  const size_t o_offs   = 35896576;   // 438,144
  const size_t o_elist  = 36334720;   // 8,755,200
  const size_t o_G0     = 45089920;   // 384,000
  const size_t o_hp     = 45473920;   // 2,048 (no init needed)
  const size_t o_ylast  = 45475968;   // 1,024
  const size_t o_HS2    = 45476992;   // 437,760
  const size_t o_HD2    = 45914752;   // 437,760
  const size_t total    = 46352512;
  if (ws_size < total) return;  // leaves d_out poisoned -> visible failure

  char* ws = (char*)d_ws;
  float*    Gpart  = (float*)(ws + o_Gpart);
  float*    Hbuf   = (float*)(ws + o_H);
  float*    HS     = (float*)(ws + o_HS);
  float*    HD     = (float*)(ws + o_HD);
  float*    H2     = (float*)(ws + o_H2);
  unsigned* X2h    = (unsigned*)(ws + o_X2h);
  int*      flags  = (int*)(ws + o_flags);
  int*      offs   = (int*)(ws + o_offs);
  int*      elist  = (int*)(ws + o_elist);
  float*    G0     = (float*)(ws + o_G0);
  unsigned* hp     = (unsigned*)(ws + o_hp);
  float*    ylast  = (float*)(ws + o_ylast);
  float*    HS2    = (float*)(ws + o_HS2);
  float*    HD2    = (float*)(ws + o_HD2);

  // only flags need zeroing (256 B)
  (void)hipMemsetAsync(flags, 0, 256, stream);

  // GAT-1 feature transform || per-graph CSR build (one grid)
  k_featcsr<<<FEATB + T_, 256, 0, stream>>>(nodes, W1, as1, ad1,
                                            Hbuf, HS, HD, ei, offs, elist);
  // GAT-1 aggregate + GAT-2 feature (LDS-resident per graph)
  k_aggrfeat<<<T_, 256, 0, stream>>>(Hbuf, HS, HD, offs, elist, b1,
                                     W2, as2, ad2, H2, HS2, HD2);
  // GAT-2 aggregate (LDS-resident; emits packed f16 X)
  k_aggr<<<T_, 256, 0, stream>>>(H2, HS2, HD2, offs, elist, b2, X2h);
  // LSTM0 input projection (f16 dot2, SPLITK=60, pre-packed X)
  k_gemm<<<dim3(32, SPLITK), 128, 0, stream>>>(X2h, Wih0, Gpart);
  k_gred<<<(T_ * G4_ + 255) / 256, 256, 0, stream>>>(Gpart, bih0, bhh0, G0);
  // 8-WG register-resident recurrence (R8-proven)
  k_lstm<<<8, 512, 0, stream>>>(G0, Whh0, Wih1, Whh1, bih1, bhh1, h0, c0,
                                hp, flags, ylast);
  // FC heads
  k_fc<<<OUT_, 256, 0, stream>>>(ylast, fW1, fb1, fW2, fb2, fW3, fb3, fW4, fb4, out);
}

// Round 21
// 960.926 us; speedup vs baseline: 1.6839x; 1.6839x over previous
//
#include <hip/hip_runtime.h>

#define T_ 96
#define N_ 1140
#define F_ 64
#define H_ 32
#define E_ 22800
#define LH_ 250
#define G4_ 1000
#define OUT_ 2280
#define KIN_ 36480   // N_*H_
#define KINH 18240   // KIN_/2 (f16 pairs)
#define SPLITK 60
#define KC 32
#define BN 32
#define FEATB 13680  // feat blocks (109440 rows / 8)

typedef _Float16 h2_t __attribute__((ext_vector_type(2)));

__device__ __forceinline__ float leaky02(float x){ return x > 0.f ? x : 0.2f*x; }
__device__ __forceinline__ float fsigm(float x){ return 1.f/(1.f + __expf(-x)); }
__device__ __forceinline__ float ftanh(float x){
  x = fminf(fmaxf(x, -15.f), 15.f);
  float t = __expf(2.f * x);
  return (t - 1.f) / (t + 1.f);
}
__device__ __forceinline__ unsigned packh2(float a, float b) {
  auto p = __builtin_amdgcn_cvt_pkrtz(a, b);   // __fp16 ext_vector(2)
  return __builtin_bit_cast(unsigned, p);
}
__device__ __forceinline__ float fdot2u(unsigned w, unsigned h, float acc) {
  return __builtin_amdgcn_fdot2(__builtin_bit_cast(h2_t, w),
                                __builtin_bit_cast(h2_t, h), acc, false);
}

// relaxed agent-scope atomics -> sc1 ops at the coherence point, no L2 wb/inv
__device__ __forceinline__ void st_agent_u(unsigned* p, unsigned v) {
  __hip_atomic_store(p, v, __ATOMIC_RELAXED, __HIP_MEMORY_SCOPE_AGENT);
}
__device__ __forceinline__ unsigned ld_agent_u(const unsigned* p) {
  return __hip_atomic_load((unsigned*)p, __ATOMIC_RELAXED, __HIP_MEMORY_SCOPE_AGENT);
}
__device__ __forceinline__ void st_agent_i(int* p, int v) {
  __hip_atomic_store(p, v, __ATOMIC_RELAXED, __HIP_MEMORY_SCOPE_AGENT);
}
__device__ __forceinline__ int ld_agent_i(const int* p) {
  return __hip_atomic_load((int*)p, __ATOMIC_RELAXED, __HIP_MEMORY_SCOPE_AGENT);
}

// -- fused grid: GAT-1 feature (blocks 0..FEATB-1) || per-graph CSR build --
__global__ void k_featcsr(const float* __restrict__ x, const float* __restrict__ W,
                          const float* __restrict__ as_, const float* __restrict__ ad_,
                          float* __restrict__ Hout, float* __restrict__ HS,
                          float* __restrict__ HD,
                          const int* __restrict__ ei, int* __restrict__ offs,
                          int* __restrict__ elist) {
  __shared__ float Wl[F_ * H_];
  __shared__ float asl[32], adl[32];
  __shared__ int cnt[N_], cur[N_], sh[256];
  int tid = threadIdx.x;
  if (blockIdx.x >= FEATB) {
    // ---------- CSR build for graph t ----------
    int t = blockIdx.x - FEATB;
    const int* srcp = ei + (size_t)t * 2 * E_;
    const int* dstp = srcp + E_;
    for (int i = tid; i < N_; i += 256) cnt[i] = 0;
    __syncthreads();
    for (int k = tid; k < E_; k += 256) atomicAdd(&cnt[dstp[k]], 1);
    __syncthreads();
    // scan (1140 = 256 threads x 5)
    int base = tid * 5;
    int v[5]; int s = 0;
    #pragma unroll
    for (int r = 0; r < 5; ++r) {
      int i = base + r;
      int c = (i < N_) ? cnt[i] : 0;
      v[r] = c; s += c;
    }
    sh[tid] = s; __syncthreads();
    for (int off = 1; off < 256; off <<= 1) {
      int add = (tid >= off) ? sh[tid - off] : 0;
      __syncthreads();
      sh[tid] += add;
      __syncthreads();
    }
    int run = sh[tid] - s;
    #pragma unroll
    for (int r = 0; r < 5; ++r) {
      int i = base + r;
      if (i < N_) { offs[t * (N_ + 1) + i] = run; cur[i] = run; }
      run += v[r];
    }
    if (tid == 255) offs[t * (N_ + 1) + N_] = sh[255];
    __syncthreads();
    // fill with LDS cursors
    int* elt = elist + (size_t)t * E_;
    for (int k = tid; k < E_; k += 256) {
      int src = srcp[k];
      int pos = atomicAdd(&cur[dstp[k]], 1);
      elt[pos] = src;
    }
    return;
  }
  // ---------- GAT-1 feature transform ----------
  for (int i = tid; i < F_ * H_; i += 256) Wl[i] = W[i];
  if (tid < 32) { asl[tid] = as_[tid]; adl[tid] = ad_[tid]; }
  __syncthreads();
  int row = blockIdx.x * 8 + (tid >> 5);
  int c = tid & 31;
  const float4* xr = (const float4*)(x + (size_t)row * F_);
  float acc = 0.f;
  for (int k4 = 0; k4 < (F_ >> 2); ++k4) {
    float4 v = xr[k4];
    acc += v.x * Wl[(4 * k4 + 0) * H_ + c];
    acc += v.y * Wl[(4 * k4 + 1) * H_ + c];
    acc += v.z * Wl[(4 * k4 + 2) * H_ + c];
    acc += v.w * Wl[(4 * k4 + 3) * H_ + c];
  }
  Hout[(size_t)row * H_ + c] = acc;
  float ps = acc * asl[c], pd = acc * adl[c];
  #pragma unroll
  for (int off = 16; off > 0; off >>= 1) {
    ps += __shfl_xor(ps, off, 32);
    pd += __shfl_xor(pd, off, 32);
  }
  if (c == 0) { HS[row] = ps; HD[row] = pd; }
}

// ------ fused: GAT-1 aggregate (chunk-softmax) + GAT-2 feature -------------
// R19-proven structure: 13680 blocks, global gathers, chunk-parallel softmax.
__global__ void k_aggrfeat(const float* __restrict__ Hf, const float* __restrict__ HS,
                           const float* __restrict__ HD, const int* __restrict__ offs,
                           const int* __restrict__ elist, const float* __restrict__ b,
                           const float* __restrict__ W2, const float* __restrict__ as2,
                           const float* __restrict__ ad2,
                           float* __restrict__ H2, float* __restrict__ HS2,
                           float* __restrict__ HD2) {
  __shared__ float W2l[H_ * H_];
  __shared__ float as2l[32], ad2l[32];
  int tid = threadIdx.x;
  for (int i = tid; i < H_ * H_; i += 256) W2l[i] = W2[i];
  if (tid < 32) { as2l[tid] = as2[tid]; ad2l[tid] = ad2[tid]; }
  __syncthreads();
  int gid = blockIdx.x * 256 + tid;
  int row = gid >> 5; int c = gid & 31;
  if (row >= T_ * N_) return;
  int t = row / N_; int i = row - t * N_;
  float hd_i = HD[row];
  float m = leaky02(HS[row] + hd_i);   // self-loop
  float s = 1.f;
  float acc = Hf[(size_t)row * H_ + c];
  int e0 = offs[t * (N_ + 1) + i], e1 = offs[t * (N_ + 1) + i + 1];
  const int* el = elist + (size_t)t * E_;
  const float* Ht = Hf + (size_t)t * N_ * H_;
  const float* HSt = HS + t * N_;
  for (int base = e0; base < e1; base += 32) {
    int e = base + c;
    bool valid = (e < e1);
    int src = valid ? el[e] : 0;
    float eg = valid ? leaky02(HSt[src] + hd_i) : -1e30f;
    float M = eg;
    #pragma unroll
    for (int off = 16; off > 0; off >>= 1) M = fmaxf(M, __shfl_xor(M, off, 32));
    float mn = fmaxf(m, M);
    float scl = __expf(m - mn);
    float p = __expf(eg - mn);             // invalid lanes -> 0
    float ps = p;
    #pragma unroll
    for (int off = 16; off > 0; off >>= 1) ps += __shfl_xor(ps, off, 32);
    s = s * scl + ps;
    acc *= scl;
    int cnt = e1 - base; if (cnt > 32) cnt = 32;
    for (int l = 0; l < cnt; ++l) {
      float pb = __shfl(p, l, 32);
      int sb = __shfl(src, l, 32);
      acc += pb * Ht[(size_t)sb * H_ + c];  // independent, coalesced loads
    }
    m = mn;
  }
  float val = fmaxf(acc / s + b[c], 0.f);   // relu'd X1[row][c], in-register
  // ---- GAT-2 feature: H2[row][c'] = sum_c val_c * W2[c][c'] ----
  float acc2 = 0.f;
  #pragma unroll
  for (int cc = 0; cc < 32; ++cc) {
    float xc = __shfl(val, cc, 32);
    acc2 += xc * W2l[cc * H_ + c];
  }
  H2[(size_t)row * H_ + c] = acc2;
  float ps2 = acc2 * as2l[c], pd2 = acc2 * ad2l[c];
  #pragma unroll
  for (int off = 16; off > 0; off >>= 1) {
    ps2 += __shfl_xor(ps2, off, 32);
    pd2 += __shfl_xor(pd2, off, 32);
  }
  if (c == 0) { HS2[row] = ps2; HD2[row] = pd2; }
}

// ------ GAT-2 aggregate (chunk-softmax); emits f16-packed X2h --------------
__global__ void k_aggr(const float* __restrict__ Hf, const float* __restrict__ HS,
                       const float* __restrict__ HD, const int* __restrict__ offs,
                       const int* __restrict__ elist, const float* __restrict__ b,
                       unsigned* __restrict__ X2h) {
  int gid = blockIdx.x * blockDim.x + threadIdx.x;
  int row = gid >> 5; int c = gid & 31;
  if (row >= T_ * N_) return;
  int t = row / N_; int i = row - t * N_;
  float hd_i = HD[row];
  float m = leaky02(HS[row] + hd_i);   // self-loop
  float s = 1.f;
  float acc = Hf[(size_t)row * H_ + c];
  int e0 = offs[t * (N_ + 1) + i], e1 = offs[t * (N_ + 1) + i + 1];
  const int* el = elist + (size_t)t * E_;
  const float* Ht = Hf + (size_t)t * N_ * H_;
  const float* HSt = HS + t * N_;
  for (int base = e0; base < e1; base += 32) {
    int e = base + c;
    bool valid = (e < e1);
    int src = valid ? el[e] : 0;
    float eg = valid ? leaky02(HSt[src] + hd_i) : -1e30f;
    float M = eg;
    #pragma unroll
    for (int off = 16; off > 0; off >>= 1) M = fmaxf(M, __shfl_xor(M, off, 32));
    float mn = fmaxf(m, M);
    float scl = __expf(m - mn);
    float p = __expf(eg - mn);
    float ps = p;
    #pragma unroll
    for (int off = 16; off > 0; off >>= 1) ps += __shfl_xor(ps, off, 32);
    s = s * scl + ps;
    acc *= scl;
    int cnt = e1 - base; if (cnt > 32) cnt = 32;
    for (int l = 0; l < cnt; ++l) {
      float pb = __shfl(p, l, 32);
      int sb = __shfl(src, l, 32);
      acc += pb * Ht[(size_t)sb * H_ + c];
    }
    m = mn;
  }
  float val = acc / s + b[c];
  // pack f16 pairs (same quantization k_gemm applied before -> G0 identical)
  int cp = c & ~1;
  float v0 = __shfl(val, cp, 32);
  float v1 = __shfl(val, cp + 1, 32);
  if ((c & 1) == 0)
    X2h[(size_t)t * KINH + i * 16 + (c >> 1)] = packh2(v0, v1);
}

// ------- LSTM0 input GEMM (f16 dot2), X pre-packed: halves X traffic -------
__global__ void k_gemm(const unsigned* __restrict__ Xh, const float* __restrict__ Wih,
                       float* __restrict__ Gpart) {
  __shared__ unsigned Xs[T_][KC / 2 + 1];   // f16 pairs along K
  __shared__ unsigned Ws[BN][KC / 2 + 1];
  int j0 = blockIdx.x * BN;
  int sp = blockIdx.y;
  int tid = threadIdx.x;
  int jj = tid & 7;    // 8 j-groups of 4
  int tt = tid >> 3;   // 16 t-groups of 6
  float acc[6][4] = {};
  int kbeg = sp * (KIN_ / SPLITK);
  int kend = kbeg + (KIN_ / SPLITK);
  for (int k0 = kbeg; k0 < kend; k0 += KC) {
    for (int idx = tid; idx < T_ * (KC / 2); idx += 128) {
      int tr = idx >> 4; int kk = idx & 15;
      Xs[tr][kk] = Xh[(size_t)tr * KINH + (k0 >> 1) + kk];
    }
    for (int idx = tid; idx < BN * (KC / 2); idx += 128) {
      int jr = idx >> 4; int kk = idx & 15;
      int j = j0 + jr;
      unsigned v = 0;
      if (j < G4_) {
        const float2 w = *(const float2*)(Wih + (size_t)j * KIN_ + k0 + 2 * kk);
        v = packh2(w.x, w.y);
      }
      Ws[jr][kk] = v;
    }
    __syncthreads();
    for (int kk = 0; kk < KC / 2; ++kk) {
      unsigned xv[6], wv[4];
      #pragma unroll
      for (int r = 0; r < 6; ++r) xv[r] = Xs[tt * 6 + r][kk];
      #pragma unroll
      for (int q = 0; q < 4; ++q) wv[q] = Ws[jj * 4 + q][kk];
      #pragma unroll
      for (int r = 0; r < 6; ++r)
        #pragma unroll
        for (int q = 0; q < 4; ++q)
          acc[r][q] = fdot2u(wv[q], xv[r], acc[r][q]);
    }
    __syncthreads();
  }
  #pragma unroll
  for (int r = 0; r < 6; ++r) {
    int t = tt * 6 + r;
    #pragma unroll
    for (int q = 0; q < 4; ++q) {
      int j = j0 + jj * 4 + q;
      if (j < G4_) Gpart[((size_t)sp * T_ + t) * 1024 + j] = acc[r][q];
    }
  }
}

// G0 reduced with gate-interleaved layout: G0[t*1000 + j*4 + g]
__global__ void k_gred(const float* __restrict__ Gpart, const float* __restrict__ bih,
                       const float* __restrict__ bhh, float* __restrict__ G0) {
  int idx = blockIdx.x * blockDim.x + threadIdx.x;
  if (idx >= T_ * G4_) return;
  int t = idx / G4_; int jg = idx - t * G4_;
  int j = jg >> 2, g = jg & 3;
  int c = g * LH_ + j;                      // gate-major column in Gpart
  float s = bih[c] + bhh[c];
  for (int sp = 0; sp < SPLITK; ++sp) s += Gpart[((size_t)sp * T_ + t) * 1024 + c];
  G0[idx] = s;
}

// ---------------- 8-WG register-resident 2-layer LSTM (R8-proven) ----------
__global__ void __launch_bounds__(512, 2) k_lstm(
    const float* __restrict__ G0, const float* __restrict__ Whh0,
    const float* __restrict__ Wih1, const float* __restrict__ Whh1,
    const float* __restrict__ bih1, const float* __restrict__ bhh1,
    const float* __restrict__ h0in, const float* __restrict__ c0in,
    unsigned* __restrict__ hp,     // [2 slots][2 layers][128] f16-pairs
    int* __restrict__ flags,       // [8], zeroed by memset
    float* __restrict__ ylast) {
  int tid = threadIdx.x;
  int bid = blockIdx.x;
  int wv = bid * 8 + (tid >> 6);   // 0..63
  int lane = tid & 63;
  int qg = lane >> 4;              // gate: 0=i 1=f 2=g 3=o
  int ql = lane & 15;

  unsigned w0[4][8], wx1[4][8], wh1[4][8];
  float bs1[4], c0l[4], c1l[4];
  bool act[4];
  #pragma unroll
  for (int u = 0; u < 4; ++u) {
    int U = wv * 4 + u;
    act[u] = (U < LH_);
    int Uc = act[u] ? U : 0;
    size_t rb = (size_t)(qg * LH_ + Uc) * LH_;
    #pragma unroll
    for (int m = 0; m < 8; ++m) {
      int pi = m * 16 + ql;
      if (act[u] && pi < 125) {
        w0[u][m]  = packh2(Whh0[rb + 2 * pi], Whh0[rb + 2 * pi + 1]);
        wx1[u][m] = packh2(Wih1[rb + 2 * pi], Wih1[rb + 2 * pi + 1]);
        wh1[u][m] = packh2(Whh1[rb + 2 * pi], Whh1[rb + 2 * pi + 1]);
      } else { w0[u][m] = 0; wx1[u][m] = 0; wh1[u][m] = 0; }
    }
    bs1[u] = act[u] ? (bih1[qg * LH_ + Uc] + bhh1[qg * LH_ + Uc]) : 0.f;
    c0l[u] = act[u] ? c0in[Uc] : 0.f;
    c1l[u] = act[u] ? c0in[LH_ + Uc] : 0.f;
  }

  float gpre[4];
  #pragma unroll
  for (int u = 0; u < 4; ++u)
    gpre[u] = act[u] ? G0[0 * G4_ + (wv * 4 + u) * 4 + qg] : 0.f;

  for (int p = 0; p <= T_; ++p) {
    int rs = (p - 1) & 1, wslot = p & 1;
    unsigned x0p[8], h1p[8];
    // x0p = h0[p-1] (= layer0 recurrent input AND layer1 x input)
    if (p == 0) {
      #pragma unroll
      for (int m = 0; m < 8; ++m) {
        int pi = m * 16 + ql;
        x0p[m] = (pi < 125) ? packh2(h0in[2 * pi], h0in[2 * pi + 1]) : 0u;
      }
    } else {
      #pragma unroll
      for (int m = 0; m < 8; ++m)
        x0p[m] = ld_agent_u(&hp[rs * 256 + m * 16 + ql]);
      if (p == 1) {
        #pragma unroll
        for (int m = 0; m < 8; ++m) {
          int pi = m * 16 + ql;
          h1p[m] = (pi < 125) ? packh2(h0in[LH_ + 2 * pi], h0in[LH_ + 2 * pi + 1]) : 0u;
        }
      } else {
        #pragma unroll
        for (int m = 0; m < 8; ++m)
          h1p[m] = ld_agent_u(&hp[rs * 256 + 128 + m * 16 + ql]);
      }
    }

    // ---- layer 0, step p ----
    if (p < T_) {
      float h0new[4];
      #pragma unroll
      for (int u = 0; u < 4; ++u) {
        float s = 0.f;
        #pragma unroll
        for (int m = 0; m < 8; ++m) s = fdot2u(w0[u][m], x0p[m], s);
        s += __shfl_xor(s, 1); s += __shfl_xor(s, 2);
        s += __shfl_xor(s, 4); s += __shfl_xor(s, 8);
        float pre = s + gpre[u];
        float a = (qg == 2) ? ftanh(pre) : fsigm(pre);
        float ai = __shfl(a, ql);
        float af = __shfl(a, 16 + ql);
        float ag = __shfl(a, 32 + ql);
        float ao = __shfl(a, 48 + ql);
        c0l[u] = af * c0l[u] + ai * ag;
        h0new[u] = act[u] ? (ao * ftanh(c0l[u])) : 0.f;
      }
      if (lane == 0) {
        st_agent_u(&hp[wslot * 256 + 2 * wv],     packh2(h0new[0], h0new[1]));
        st_agent_u(&hp[wslot * 256 + 2 * wv + 1], packh2(h0new[2], h0new[3]));
      }
    }
    // ---- layer 1, step p-1 ----
    if (p >= 1) {
      float h1new[4];
      #pragma unroll
      for (int u = 0; u < 4; ++u) {
        float s = 0.f;
        #pragma unroll
        for (int m = 0; m < 8; ++m) s = fdot2u(wx1[u][m], x0p[m], s);
        #pragma unroll
        for (int m = 0; m < 8; ++m) s = fdot2u(wh1[u][m], h1p[m], s);
        s += __shfl_xor(s, 1); s += __shfl_xor(s, 2);
        s += __shfl_xor(s, 4); s += __shfl_xor(s, 8);
        float pre = s + bs1[u];
        float a = (qg == 2) ? ftanh(pre) : fsigm(pre);
        float bi = __shfl(a, ql);
        float bf = __shfl(a, 16 + ql);
        float bg = __shfl(a, 32 + ql);
        float bo = __shfl(a, 48 + ql);
        c1l[u] = bf * c1l[u] + bi * bg;
        h1new[u] = act[u] ? (bo * ftanh(c1l[u])) : 0.f;
      }
      if (p - 1 == T_ - 1 && lane == 0) {
        #pragma unroll
        for (int u = 0; u < 4; ++u)
          if (act[u]) ylast[wv * 4 + u] = h1new[u];
      }
      if (lane == 0) {
        st_agent_u(&hp[wslot * 256 + 128 + 2 * wv],     packh2(h1new[0], h1new[1]));
        st_agent_u(&hp[wslot * 256 + 128 + 2 * wv + 1], packh2(h1new[2], h1new[3]));
      }
    }
    // ---- prefetch next step's G0 (independent of the barrier) ----
    float gnext[4];
    #pragma unroll
    for (int u = 0; u < 4; ++u)
      gnext[u] = (p + 1 < T_ && act[u]) ? G0[(p + 1) * G4_ + (wv * 4 + u) * 4 + qg] : 0.f;
    // ---- fence-free barrier ----
    if (p < T_) {
      __syncthreads();   // implicit vmcnt drain: all sc1 stores acked
      if (tid == 0) {
        asm volatile("s_waitcnt vmcnt(0)" ::: "memory");
        st_agent_i(&flags[bid], p + 1);
      }
      if (tid < 64) {
        int guard = 0;
        for (;;) {
          int f = ld_agent_i(&flags[lane & 7]);
          if (__ballot(f >= p + 1) == ~0ULL) break;
          if (++guard > (1 << 22)) break;   // hang insurance only
          __builtin_amdgcn_s_sleep(1);
        }
      }
      __syncthreads();
    }
    #pragma unroll
    for (int u = 0; u < 4; ++u) gpre[u] = gnext[u];
  }
}

// ---------------- 4 FC heads ----------------------------------------------
__global__ void k_fc(const float* __restrict__ ylast,
                     const float* __restrict__ Wa, const float* __restrict__ ba,
                     const float* __restrict__ Wb, const float* __restrict__ bb,
                     const float* __restrict__ Wc, const float* __restrict__ bc,
                     const float* __restrict__ Wd, const float* __restrict__ bd,
                     float* __restrict__ out) {
  int wg = blockIdx.x * 4 + (threadIdx.x >> 6);
  int lane = threadIdx.x & 63;
  if (wg >= 4 * OUT_) return;
  int head = wg / OUT_, o = wg - head * OUT_;
  const float* W = head == 0 ? Wa : head == 1 ? Wb : head == 2 ? Wc : Wd;
  const float* b = head == 0 ? ba : head == 1 ? bb : head == 2 ? bc : bd;
  float s = 0.f;
  #pragma unroll
  for (int r = 0; r < 4; ++r) {
    int idx = r * 64 + lane;
    if (idx < LH_) s += ylast[idx] * W[(size_t)o * LH_ + idx];
  }
  #pragma unroll
  for (int off = 32; off > 0; off >>= 1) s += __shfl_xor(s, off, 64);
  if (lane == 0) out[wg] = s + b[o];
}

// ---------------- launch ---------------------------------------------------
extern "C" void kernel_launch(void* const* d_in, const int* in_sizes, int n_in,
                              void* d_out, int out_size, void* d_ws, size_t ws_size,
                              hipStream_t stream) {
  const float* nodes = (const float*)d_in[0];
  const int*   ei    = (const int*)d_in[1];
  const float* W1    = (const float*)d_in[3];
  const float* as1   = (const float*)d_in[4];
  const float* ad1   = (const float*)d_in[5];
  const float* b1    = (const float*)d_in[6];
  const float* W2    = (const float*)d_in[7];
  const float* as2   = (const float*)d_in[8];
  const float* ad2   = (const float*)d_in[9];
  const float* b2    = (const float*)d_in[10];
  const float* Wih0  = (const float*)d_in[11];
  const float* Whh0  = (const float*)d_in[12];
  const float* bih0  = (const float*)d_in[13];
  const float* bhh0  = (const float*)d_in[14];
  const float* Wih1  = (const float*)d_in[15];
  const float* Whh1  = (const float*)d_in[16];
  const float* bih1  = (const float*)d_in[17];
  const float* bhh1  = (const float*)d_in[18];
  const float* h0    = (const float*)d_in[19];
  const float* c0    = (const float*)d_in[20];
  const float* fW1   = (const float*)d_in[21];
  const float* fb1   = (const float*)d_in[22];
  const float* fW2   = (const float*)d_in[23];
  const float* fb2   = (const float*)d_in[24];
  const float* fW3   = (const float*)d_in[25];
  const float* fb3   = (const float*)d_in[26];
  const float* fW4   = (const float*)d_in[27];
  const float* fb4   = (const float*)d_in[28];
  float* out = (float*)d_out;

  // workspace layout (bytes). Gpart overlaps the dead H1/HS/HD/H2 prefix.
  const size_t o_Gpart  = 0;          // 23,592,960
  const size_t o_H      = 0;          // H1 14,008,320
  const size_t o_HS     = 14008320;   // 437,760
  const size_t o_HD     = 14446080;   // 437,760
  const size_t o_H2     = 14883840;   // 14,008,320
  const size_t o_X2h    = 28892160;   // 96*18240*4 = 7,004,160 (f16 pairs)
  const size_t o_flags  = 35896320;   // 256
  const size_t o_offs   = 35896576;   // 438,144
  const size_t o_elist  = 36334720;   // 8,755,200
  const size_t o_G0     = 45089920;   // 384,000
  const size_t o_hp     = 45473920;   // 2,048 (no init needed)
  const size_t o_ylast  = 45475968;   // 1,024
  const size_t o_HS2    = 45476992;   // 437,760
  const size_t o_HD2    = 45914752;   // 437,760
  const size_t total    = 46352512;
  if (ws_size < total) return;  // leaves d_out poisoned -> visible failure

  char* ws = (char*)d_ws;
  float*    Gpart  = (float*)(ws + o_Gpart);
  float*    Hbuf   = (float*)(ws + o_H);
  float*    HS     = (float*)(ws + o_HS);
  float*    HD     = (float*)(ws + o_HD);
  float*    H2     = (float*)(ws + o_H2);
  unsigned* X2h    = (unsigned*)(ws + o_X2h);
  int*      flags  = (int*)(ws + o_flags);
  int*      offs   = (int*)(ws + o_offs);
  int*      elist  = (int*)(ws + o_elist);
  float*    G0     = (float*)(ws + o_G0);
  unsigned* hp     = (unsigned*)(ws + o_hp);
  float*    ylast  = (float*)(ws + o_ylast);
  float*    HS2    = (float*)(ws + o_HS2);
  float*    HD2    = (float*)(ws + o_HD2);

  // only flags need zeroing (256 B)
  (void)hipMemsetAsync(flags, 0, 256, stream);

  const int rows_grid = (T_ * N_ * H_) / 256;   // 13680

  // GAT-1 feature transform || per-graph CSR build (one grid)
  k_featcsr<<<FEATB + T_, 256, 0, stream>>>(nodes, W1, as1, ad1,
                                            Hbuf, HS, HD, ei, offs, elist);
  // GAT-1 aggregate + GAT-2 feature (R19-proven chunk-softmax)
  k_aggrfeat<<<rows_grid, 256, 0, stream>>>(Hbuf, HS, HD, offs, elist, b1,
                                            W2, as2, ad2, H2, HS2, HD2);
  // GAT-2 aggregate (chunk-softmax; emits packed f16 X)
  k_aggr<<<rows_grid, 256, 0, stream>>>(H2, HS2, HD2, offs, elist, b2, X2h);
  // LSTM0 input projection (f16 dot2, SPLITK=60, pre-packed X)
  k_gemm<<<dim3(32, SPLITK), 128, 0, stream>>>(X2h, Wih0, Gpart);
  k_gred<<<(T_ * G4_ + 255) / 256, 256, 0, stream>>>(Gpart, bih0, bhh0, G0);
  // 8-WG register-resident recurrence (R8-proven)
  k_lstm<<<8, 512, 0, stream>>>(G0, Whh0, Wih1, Whh1, bih1, bhh1, h0, c0,
                                hp, flags, ylast);
  // FC heads
  k_fc<<<OUT_, 256, 0, stream>>>(ylast, fW1, fb1, fW2, fb2, fW3, fb3, fW4, fb4, out);
}